// Round 11
// baseline (118.102 us; speedup 1.0000x reference)
//
#include <hip/hip_runtime.h>
#include <math.h>

#define N_G 512
#define IMG_H 324
#define IMG_W 332
#define N_C 120
#define HW (IMG_H*IMG_W)
#define CHUNK 32               // LDS ~40 KB -> 4 blocks/CU
#define TSX 21                 // tiles in x (16 px)
#define TSY 81                 // tiles in y (4 px)
#define NT (TSX*TSY)

// ONE 256-thread block per 16x4 tile (was 4 channel-split blocks).
// Rationale (r10 post-mortem): total tile-hits are only ~10-15K (gaussians
// cluster near image center), so phase work is small; the dominant cost was
// per-block FIXED overhead (project all 512 gaussians, build, rank-scan,
// epilogue) x 6804 blocks. Merging to 1701 blocks cuts that 4x. Each wave
// now owns 8 interleaved float4 channel groups (c = 4w + 16k; waves 2,3: 7).
// Phase B stays a branch-free COUNTED loop (r10 lesson) reading BROADCAST
// b128 from LDS-staged spec rows (r6 lesson: never per-wave global loads).
// Alpha/T-chain per wave in registers; T bitwise-identical across waves ->
// chunk-end early-stop ballot is wave-uniform (safe with barriers).

__global__ __launch_bounds__(256, 4) void k_render(
    const float* __restrict__ pos, const float* __restrict__ scales,
    const float* __restrict__ opac, const float* __restrict__ Km,
    const float* __restrict__ Em, const float* __restrict__ spec,
    const float* __restrict__ tm, float* __restrict__ out)
{
  __shared__ __align__(16) float prm[N_G*8];      // rank-sorted hit params (16 KB)
  __shared__ __align__(16) float buf[CHUNK*64];   // keys during build; alpha (8 KB)
  __shared__ __align__(16) float sbuf[CHUNK*N_C]; // staged 120-ch rows (15 KB)
  __shared__ int wcnt[4];
  // total ~40 KB -> 4 blocks/CU (16 waves/CU)

  const int tid  = threadIdx.x;
  const int w    = tid >> 6;
  const int lane = tid & 63;
  const int tx = lane & 15, ty = lane >> 4;
  const unsigned long long ltm = (1ull << lane) - 1ull;

  const int t = blockIdx.x;             // tile

  // ---- prep: project 2 gaussians per thread into registers ----
  float psx[2], psy[2], pc00[2], pc11[2], pl2[2], pd[2];
  float bxmin[2], bxmax[2], bymin[2], bymax[2];
  {
    const float E0=Em[0],E1=Em[1],E2=Em[2],E3=Em[3],
                E4=Em[4],E5=Em[5],E6=Em[6],E7=Em[7],
                E8=Em[8],E9=Em[9],E10=Em[10],E11=Em[11];
    const float K0=Km[0],K1=Km[1],K2=Km[2],
                K3=Km[3],K4=Km[4],K5=Km[5],
                K6=Km[6],K7=Km[7],K8=Km[8];
    #pragma unroll
    for (int q = 0; q < 2; ++q) {
      const int g = w*128 + lane + q*64;           // original index (wave-major)
      float p0 = pos[g*3+0], p1 = pos[g*3+1], p2 = pos[g*3+2];
      float cam0 = E0*p0 + E1*p1 + E2*p2  + E3;
      float cam1 = E4*p0 + E5*p1 + E6*p2  + E7;
      float cam2 = E8*p0 + E9*p1 + E10*p2 + E11;
      float pr0 = K0*cam0 + K1*cam1 + K2*cam2;
      float pr1 = K3*cam0 + K4*cam1 + K5*cam2;
      float pr2 = K6*cam0 + K7*cam1 + K8*cam2;
      float inv = 1.0f/(pr2 + 1e-6f);
      float sx = pr0*inv, sy = pr1*inv;
      float depth = cam2;
      bool valid = (depth > 0.01f) && (depth < 100.0f)
                && (sx > -100.0f) && (sx < (float)IMG_W + 100.0f)
                && (sy > -100.0f) && (sy < (float)IMG_H + 100.0f);
      bool off = (sx < -(float)IMG_W) || (sx > 2.0f*(float)IMG_W)
              || (sy < -(float)IMG_H) || (sy > 2.0f*(float)IMG_H);
      bool skip = off || (!valid);
      float s0 = scales[g*3+0], s1 = scales[g*3+1];
      float v0 = s0*s0 + 1e-4f, v1 = s1*s1 + 1e-4f;
      const float HL2E = 0.72134752f;              // 0.5*log2(e)
      psx[q] = sx; psy[q] = sy;
      pc00[q] = HL2E/v0; pc11[q] = HL2E/v1;
      pl2[q] = __log2f(skip ? 0.0f : opac[g]);     // op=0 -> -inf -> exp2 -> 0
      pd[q]  = depth;
      float rx = 6.0f*sqrtf(v0);                   // mahal cutoff 36 (6 sigma)
      float ry = 6.0f*sqrtf(v1);
      bxmin[q] = skip ?  1e9f : sx - rx;
      bxmax[q] = skip ? -1e9f : sx + rx;
      bymin[q] = skip ?  1e9f : sy - ry;
      bymax[q] = skip ? -1e9f : sy + ry;
    }
  }

  // center-out bijection: heavy central tiles get the lowest blockIdx
  const int jx = t % TSX, ky = t / TSX;
  const int bx = 10 + ((jx & 1) ? ((jx+1)>>1) : -((jx+1)>>1));
  const int by = 40 + ((ky & 1) ? ((ky+1)>>1) : -((ky+1)>>1));

  const int x = bx*16 + tx;
  const int y = by*4 + ty;
  const bool inb = (x < IMG_W) && (y < IMG_H);
  const float px = (float)min(x, IMG_W-1);
  const float py = (float)min(y, IMG_H-1);
  const float wxmin = (float)(bx*16), wxmax = wxmin + 15.0f;
  const float wymin = (float)(by*4),  wymax = wymin + 3.0f;

  // ---- build: AABB + ellipse nearest-point prune, compaction, rank-sort ----
  bool h0 = !(bxmin[0] > wxmax || bxmax[0] < wxmin ||
              bymin[0] > wymax || bymax[0] < wymin);
  bool h1 = !(bxmin[1] > wxmax || bxmax[1] < wxmin ||
              bymin[1] > wymax || bymax[1] < wymin);
  {
    // nearest point of tile box to center; emax bounds e over all pixels
    float nx0 = fminf(fmaxf(psx[0], wxmin), wxmax);
    float ny0 = fminf(fmaxf(psy[0], wymin), wymax);
    float dx0 = nx0 - psx[0], dy0 = ny0 - psy[0];
    h0 = h0 && (pl2[0] - (pc00[0]*dx0*dx0 + pc11[0]*dy0*dy0) > -24.0f);
    float nx1 = fminf(fmaxf(psx[1], wxmin), wxmax);
    float ny1 = fminf(fmaxf(psy[1], wymin), wymax);
    float dx1 = nx1 - psx[1], dy1 = ny1 - psy[1];
    h1 = h1 && (pl2[1] - (pc00[1]*dx1*dx1 + pc11[1]*dy1*dy1) > -24.0f);
  }
  unsigned long long m0 = __ballot(h0), m1 = __ballot(h1);
  int c0 = __popcll(m0);
  if (lane == 0) wcnt[w] = c0 + __popcll(m1);
  __syncthreads();
  int offw = 0;
  #pragma unroll
  for (int k = 0; k < 4; ++k) if (k < w) offw += wcnt[k];
  const int nh = wcnt[0] + wcnt[1] + wcnt[2] + wcnt[3];
  // compacted depth keys (compaction order == original-index order)
  const int p0 = offw + __popcll(m0 & ltm);
  const int p1 = offw + c0 + __popcll(m1 & ltm);
  if (h0) buf[p0] = pd[0];
  if (h1) buf[p1] = pd[1];
  if (tid < 4) buf[nh + tid] = 1e30f;            // pad for float4 scan
  __syncthreads();

  // rank-scan (broadcast b128 reads); stable tie-break by compacted position
  if (h0 | h1) {
    int r0 = 0, r1 = 0;
    const float d0 = pd[0], d1 = pd[1];
    for (int j = 0; j < nh; j += 4) {
      float4 k4 = *(const float4*)&buf[j];
      if (h0) {
        r0 += (k4.x < d0 || (k4.x == d0 && j+0 < p0)) ? 1 : 0;
        r0 += (k4.y < d0 || (k4.y == d0 && j+1 < p0)) ? 1 : 0;
        r0 += (k4.z < d0 || (k4.z == d0 && j+2 < p0)) ? 1 : 0;
        r0 += (k4.w < d0 || (k4.w == d0 && j+3 < p0)) ? 1 : 0;
      }
      if (h1) {
        r1 += (k4.x < d1 || (k4.x == d1 && j+0 < p1)) ? 1 : 0;
        r1 += (k4.y < d1 || (k4.y == d1 && j+1 < p1)) ? 1 : 0;
        r1 += (k4.z < d1 || (k4.z == d1 && j+2 < p1)) ? 1 : 0;
        r1 += (k4.w < d1 || (k4.w == d1 && j+3 < p1)) ? 1 : 0;
      }
    }
    if (h0) {
      *(float4*)&prm[r0*8]   = make_float4(psx[0], psy[0], pc00[0], pc11[0]);
      *(float4*)&prm[r0*8+4] = make_float4(pl2[0], pd[0],
                                 __int_as_float((w*128 + lane)*N_C), 0.0f);
    }
    if (h1) {
      *(float4*)&prm[r1*8]   = make_float4(psx[1], psy[1], pc00[1], pc11[1]);
      *(float4*)&prm[r1*8+4] = make_float4(pl2[1], pd[1],
                                 __int_as_float((w*128 + lane + 64)*N_C), 0.0f);
    }
  }
  __syncthreads();

  float T = 1.0f, dacc = 0.0f;          // T bitwise-identical across waves
  // wave w owns float4 channel groups c = 4w + 16k, k = 0..7 (w>=2: k<=6)
  float4 acc[8] = {};
  const int ng = (w < 2) ? 8 : 7;       // 8+8+7+7 = 30 groups = 120 channels
  const int cw = 4*w;

  for (int cb = 0; cb < nh; cb += CHUNK) {
    const int nc = min(CHUNK, nh - cb);

    // ---- phase A: alpha + 120-ch staging (8 rows per wave) ----
    #pragma unroll 2
    for (int j = w; j < nc; j += 4) {
      float4 q0 = *(const float4*)&prm[(cb+j)*8];     // ds_read_b128
      float4 q1 = *(const float4*)&prm[(cb+j)*8+4];
      float dx = px - q0.x, dy = py - q0.y;
      float m = q0.z*dx*dx + q0.w*dy*dy;              // log2-units
      buf[j*64 + lane] = exp2f(q1.x - m);             // raw alpha
      int sbase = __float_as_int(q1.z);               // src*120 (coalesced)
      sbuf[j*N_C + lane] = spec[sbase + lane];
      if (lane < N_C - 64) sbuf[j*N_C + 64 + lane] = spec[sbase + 64 + lane];
    }
    __syncthreads();

    // ---- phase B: branch-free counted loop; 8 broadcast b128 + 32 fma ----
    #pragma unroll 2
    for (int j = 0; j < nc; ++j) {
      float a  = buf[j*64 + lane];                    // conflict-free b32
      float wv = a * T;
      T *= (1.0f - a);
      if (w == 0)                                     // wave-uniform branch
        dacc = fmaf(prm[(cb+j)*8+5], wv, dacc);       // depth accum
      const float* row = &sbuf[j*N_C + cw];           // broadcast b128 reads
      #pragma unroll
      for (int k = 0; k < 8; ++k) {
        if (k < ng) {
          float4 s4 = *(const float4*)(row + 16*k);
          acc[k].x = fmaf(wv, s4.x, acc[k].x);
          acc[k].y = fmaf(wv, s4.y, acc[k].y);
          acc[k].z = fmaf(wv, s4.z, acc[k].z);
          acc[k].w = fmaf(wv, s4.w, acc[k].w);
        }
      }
    }
    __syncthreads();   // buf/sbuf reused next chunk
    // early stop: T bitwise-identical across waves -> uniform branch (safe)
    if (!__ballot(T >= 1e-5f)) break;  // front-to-back: remainder <= T
  }

  // ---- epilogue: store wave-exclusive channel groups (no combine) ----
  if (inb) {
    const int pixi = y*IMG_W + x;
    const float bgT = T;                // BG*(1 - A_final), BG = 1.0
    #pragma unroll
    for (int k = 0; k < 8; ++k) {
      if (k < ng) {
        const int c = cw + 16*k;
        float4 t4 = *(const float4*)&tm[c];
        out[(c+0)*HW + pixi] = (acc[k].x + bgT)*t4.x;
        out[(c+1)*HW + pixi] = (acc[k].y + bgT)*t4.y;
        out[(c+2)*HW + pixi] = (acc[k].z + bgT)*t4.z;
        out[(c+3)*HW + pixi] = (acc[k].w + bgT)*t4.w;
      }
    }
    if (w == 0) out[N_C*HW + pixi] = dacc;           // depth image
    if (w == 1) out[N_C*HW + HW + pixi] = 1.0f - T;  // A_final
  }
}

extern "C" void kernel_launch(void* const* d_in, const int* in_sizes, int n_in,
                              void* d_out, int out_size, void* d_ws, size_t ws_size,
                              hipStream_t stream) {
  const float* pos    = (const float*)d_in[0];
  // d_in[1] rotations: unused by the reference
  const float* scales = (const float*)d_in[2];
  const float* opac   = (const float*)d_in[3];
  const float* spec   = (const float*)d_in[4];
  const float* tm     = (const float*)d_in[5];
  const float* K      = (const float*)d_in[6];
  const float* E      = (const float*)d_in[7];
  float* out = (float*)d_out;
  (void)d_ws; (void)ws_size;   // no workspace needed

  k_render<<<NT, 256, 0, stream>>>(pos, scales, opac, K, E, spec, tm, out);
}

// Round 12
// 109.715 us; speedup vs baseline: 1.0764x; 1.0764x over previous
//
#include <hip/hip_runtime.h>
#include <math.h>

#define N_G 512
#define IMG_H 324
#define IMG_W 332
#define N_C 120
#define HW (IMG_H*IMG_W)
#define CHUNK 24               // dbuf: LDS ~34 KB -> 4 blocks/CU
#define TSX 21                 // tiles in x (16 px)
#define TSY 81                 // tiles in y (4 px)
#define NT (TSX*TSY)
#define NBLK (NT*4)            // 4 channel-split blocks per tile

// R10 structure (best: 109.8us) + two changes:
//  (1) DOUBLE-BUFFERED chunks, ONE barrier each: stage chunk k+1 (alpha +
//      spec rows) before computing phase B of chunk k -> the staging global
//      loads' L2 latency hides under B's FMA work (critical for the lone
//      straggler block, which has no co-resident waves to hide it).
//      Safety: A(k+1) writes buffer (k+1)&1, last read by B(k-1), which all
//      waves completed before the previous barrier.
//  (2) CONTIGUOUS channel split: block cq owns channels [32cq, 32cq+32)
//      (cq3: 24). Staging = one coalesced 128B read per row (was 8 scattered
//      16B segments). Wave w owns float4 groups at 32cq+4w and +16.
// Lessons kept: counted branch-free phase B (r10), 4-way split (r11 revert),
// no mid-loop ballot (r8), LDS-staged spec (r6), ellipse prune (r9).

__global__ __launch_bounds__(256, 4) void k_render(
    const float* __restrict__ pos, const float* __restrict__ scales,
    const float* __restrict__ opac, const float* __restrict__ Km,
    const float* __restrict__ Em, const float* __restrict__ spec,
    const float* __restrict__ tm, float* __restrict__ out)
{
  __shared__ __align__(16) float prm[N_G*8];        // rank-sorted params (16 KB)
  __shared__ __align__(16) float abuf[2][CHUNK*64]; // alpha dbuf (12 KB)
  __shared__ __align__(16) float sbuf[2][CHUNK*32]; // spec-row dbuf (6 KB)
  __shared__ int wcnt[4];
  // total ~34 KB -> 4 blocks/CU (16 waves/CU)

  const int tid  = threadIdx.x;
  const int w    = tid >> 6;
  const int lane = tid & 63;
  const int tx = lane & 15, ty = lane >> 4;
  const unsigned long long ltm = (1ull << lane) - 1ull;

  const int t  = blockIdx.x >> 2;       // tile
  const int cq = blockIdx.x & 3;        // channel quarter

  // ---- prep: project 2 gaussians per thread into registers ----
  float psx[2], psy[2], pc00[2], pc11[2], pl2[2], pd[2];
  float bxmin[2], bxmax[2], bymin[2], bymax[2];
  {
    const float E0=Em[0],E1=Em[1],E2=Em[2],E3=Em[3],
                E4=Em[4],E5=Em[5],E6=Em[6],E7=Em[7],
                E8=Em[8],E9=Em[9],E10=Em[10],E11=Em[11];
    const float K0=Km[0],K1=Km[1],K2=Km[2],
                K3=Km[3],K4=Km[4],K5=Km[5],
                K6=Km[6],K7=Km[7],K8=Km[8];
    #pragma unroll
    for (int q = 0; q < 2; ++q) {
      const int g = w*128 + lane + q*64;           // original index (wave-major)
      float p0 = pos[g*3+0], p1 = pos[g*3+1], p2 = pos[g*3+2];
      float cam0 = E0*p0 + E1*p1 + E2*p2  + E3;
      float cam1 = E4*p0 + E5*p1 + E6*p2  + E7;
      float cam2 = E8*p0 + E9*p1 + E10*p2 + E11;
      float pr0 = K0*cam0 + K1*cam1 + K2*cam2;
      float pr1 = K3*cam0 + K4*cam1 + K5*cam2;
      float pr2 = K6*cam0 + K7*cam1 + K8*cam2;
      float inv = 1.0f/(pr2 + 1e-6f);
      float sx = pr0*inv, sy = pr1*inv;
      float depth = cam2;
      bool valid = (depth > 0.01f) && (depth < 100.0f)
                && (sx > -100.0f) && (sx < (float)IMG_W + 100.0f)
                && (sy > -100.0f) && (sy < (float)IMG_H + 100.0f);
      bool off = (sx < -(float)IMG_W) || (sx > 2.0f*(float)IMG_W)
              || (sy < -(float)IMG_H) || (sy > 2.0f*(float)IMG_H);
      bool skip = off || (!valid);
      float s0 = scales[g*3+0], s1 = scales[g*3+1];
      float v0 = s0*s0 + 1e-4f, v1 = s1*s1 + 1e-4f;
      const float HL2E = 0.72134752f;              // 0.5*log2(e)
      psx[q] = sx; psy[q] = sy;
      pc00[q] = HL2E/v0; pc11[q] = HL2E/v1;
      pl2[q] = __log2f(skip ? 0.0f : opac[g]);     // op=0 -> -inf -> exp2 -> 0
      pd[q]  = depth;
      float rx = 6.0f*sqrtf(v0);                   // mahal cutoff 36 (6 sigma)
      float ry = 6.0f*sqrtf(v1);
      bxmin[q] = skip ?  1e9f : sx - rx;
      bxmax[q] = skip ? -1e9f : sx + rx;
      bymin[q] = skip ?  1e9f : sy - ry;
      bymax[q] = skip ? -1e9f : sy + ry;
    }
  }

  // center-out bijection: heavy central tiles get the lowest blockIdx
  const int jx = t % TSX, ky = t / TSX;
  const int bx = 10 + ((jx & 1) ? ((jx+1)>>1) : -((jx+1)>>1));
  const int by = 40 + ((ky & 1) ? ((ky+1)>>1) : -((ky+1)>>1));

  const int x = bx*16 + tx;
  const int y = by*4 + ty;
  const bool inb = (x < IMG_W) && (y < IMG_H);
  const float px = (float)min(x, IMG_W-1);
  const float py = (float)min(y, IMG_H-1);
  const float wxmin = (float)(bx*16), wxmax = wxmin + 15.0f;
  const float wymin = (float)(by*4),  wymax = wymin + 3.0f;

  // ---- build: AABB + ellipse nearest-point prune, compaction, rank-sort ----
  bool h0 = !(bxmin[0] > wxmax || bxmax[0] < wxmin ||
              bymin[0] > wymax || bymax[0] < wymin);
  bool h1 = !(bxmin[1] > wxmax || bxmax[1] < wxmin ||
              bymin[1] > wymax || bymax[1] < wymin);
  {
    // nearest point of tile box to center; emax bounds e over all pixels
    float nx0 = fminf(fmaxf(psx[0], wxmin), wxmax);
    float ny0 = fminf(fmaxf(psy[0], wymin), wymax);
    float dx0 = nx0 - psx[0], dy0 = ny0 - psy[0];
    h0 = h0 && (pl2[0] - (pc00[0]*dx0*dx0 + pc11[0]*dy0*dy0) > -24.0f);
    float nx1 = fminf(fmaxf(psx[1], wxmin), wxmax);
    float ny1 = fminf(fmaxf(psy[1], wymin), wymax);
    float dx1 = nx1 - psx[1], dy1 = ny1 - psy[1];
    h1 = h1 && (pl2[1] - (pc00[1]*dx1*dx1 + pc11[1]*dy1*dy1) > -24.0f);
  }
  unsigned long long m0 = __ballot(h0), m1 = __ballot(h1);
  int c0 = __popcll(m0);
  if (lane == 0) wcnt[w] = c0 + __popcll(m1);
  __syncthreads();
  int offw = 0;
  #pragma unroll
  for (int k = 0; k < 4; ++k) if (k < w) offw += wcnt[k];
  const int nh = wcnt[0] + wcnt[1] + wcnt[2] + wcnt[3];
  // compacted depth keys in abuf[0] (compaction order == original order)
  float* key = abuf[0];
  const int p0 = offw + __popcll(m0 & ltm);
  const int p1 = offw + c0 + __popcll(m1 & ltm);
  if (h0) key[p0] = pd[0];
  if (h1) key[p1] = pd[1];
  if (tid < 4) key[nh + tid] = 1e30f;            // pad for float4 scan
  __syncthreads();

  // rank-scan (broadcast b128 reads); stable tie-break by compacted position
  if (h0 | h1) {
    int r0 = 0, r1 = 0;
    const float d0 = pd[0], d1 = pd[1];
    for (int j = 0; j < nh; j += 4) {
      float4 k4 = *(const float4*)&key[j];
      if (h0) {
        r0 += (k4.x < d0 || (k4.x == d0 && j+0 < p0)) ? 1 : 0;
        r0 += (k4.y < d0 || (k4.y == d0 && j+1 < p0)) ? 1 : 0;
        r0 += (k4.z < d0 || (k4.z == d0 && j+2 < p0)) ? 1 : 0;
        r0 += (k4.w < d0 || (k4.w == d0 && j+3 < p0)) ? 1 : 0;
      }
      if (h1) {
        r1 += (k4.x < d1 || (k4.x == d1 && j+0 < p1)) ? 1 : 0;
        r1 += (k4.y < d1 || (k4.y == d1 && j+1 < p1)) ? 1 : 0;
        r1 += (k4.z < d1 || (k4.z == d1 && j+2 < p1)) ? 1 : 0;
        r1 += (k4.w < d1 || (k4.w == d1 && j+3 < p1)) ? 1 : 0;
      }
    }
    if (h0) {
      *(float4*)&prm[r0*8]   = make_float4(psx[0], psy[0], pc00[0], pc11[0]);
      *(float4*)&prm[r0*8+4] = make_float4(pl2[0], pd[0],
                                 __int_as_float((w*128 + lane)*N_C), 0.0f);
    }
    if (h1) {
      *(float4*)&prm[r1*8]   = make_float4(psx[1], psy[1], pc00[1], pc11[1]);
      *(float4*)&prm[r1*8+4] = make_float4(pl2[1], pd[1],
                                 __int_as_float((w*128 + lane + 64)*N_C), 0.0f);
    }
  }
  __syncthreads();

  float T = 1.0f, dacc = 0.0f;          // T bitwise-identical across waves
  float4 acc0 = {0,0,0,0}, acc1 = {0,0,0,0};
  const int c0ch = cq*32 + 4*w;         // first group; second at +16
  const bool g1ok = (cq < 3) || (w < 2);   // cq3 has 24 channels
  const bool stok = lane < ((cq == 3) ? 24 : 32);
  const int csta = cq*32;               // contiguous staging base

  // ---- stage chunk 0 ----
  {
    const int nc0 = min(CHUNK, nh);
    #pragma unroll 2
    for (int j = w; j < nc0; j += 4) {
      float4 q0 = *(const float4*)&prm[j*8];
      float4 q1 = *(const float4*)&prm[j*8+4];
      float dx = px - q0.x, dy = py - q0.y;
      abuf[0][j*64 + lane] = exp2f(q1.x - (q0.z*dx*dx + q0.w*dy*dy));
      int sbase = __float_as_int(q1.z);               // src*120
      if (stok) sbuf[0][j*32 + lane] = spec[sbase + csta + lane];
    }
  }
  __syncthreads();

  // ---- main: double-buffered, ONE barrier per chunk ----
  for (int cb = 0, k = 0; cb < nh; cb += CHUNK, ++k) {
    const int nc  = min(CHUNK, nh - cb);
    const int cur = k & 1, nxt = cur ^ 1;

    // stage NEXT chunk first: global-load latency hides under phase B below
    const int cb2 = cb + CHUNK;
    if (cb2 < nh) {
      const int nc2 = min(CHUNK, nh - cb2);
      #pragma unroll 2
      for (int j = w; j < nc2; j += 4) {
        float4 q0 = *(const float4*)&prm[(cb2+j)*8];
        float4 q1 = *(const float4*)&prm[(cb2+j)*8+4];
        float dx = px - q0.x, dy = py - q0.y;
        abuf[nxt][j*64 + lane] = exp2f(q1.x - (q0.z*dx*dx + q0.w*dy*dy));
        int sbase = __float_as_int(q1.z);
        if (stok) sbuf[nxt][j*32 + lane] = spec[sbase + csta + lane];
      }
    }

    // phase B: branch-free counted loop on current buffer
    #pragma unroll 2
    for (int j = 0; j < nc; ++j) {
      float a  = abuf[cur][j*64 + lane];              // conflict-free b32
      float wv = a * T;
      T *= (1.0f - a);
      if (w == 0)                                     // wave-uniform branch
        dacc = fmaf(prm[(cb+j)*8+5], wv, dacc);       // depth (used by cq2)
      const float* row = &sbuf[cur][j*32 + 4*w];      // uniform b128 reads
      float4 s0 = *(const float4*)(row);
      acc0.x = fmaf(wv, s0.x, acc0.x);
      acc0.y = fmaf(wv, s0.y, acc0.y);
      acc0.z = fmaf(wv, s0.z, acc0.z);
      acc0.w = fmaf(wv, s0.w, acc0.w);
      if (g1ok) {
        float4 s1 = *(const float4*)(row + 16);
        acc1.x = fmaf(wv, s1.x, acc1.x);
        acc1.y = fmaf(wv, s1.y, acc1.y);
        acc1.z = fmaf(wv, s1.z, acc1.z);
        acc1.w = fmaf(wv, s1.w, acc1.w);
      }
    }
    __syncthreads();   // A(k+1) visible; B(k) done before A(k+2) overwrites
    // early stop: T bitwise-identical across waves -> uniform branch (safe)
    if (!__ballot(T >= 1e-5f)) break;  // front-to-back: remainder <= T
  }

  // ---- epilogue: store wave-exclusive contiguous channel groups ----
  if (inb) {
    const int pixi = y*IMG_W + x;
    const float bgT = T;                // BG*(1 - A_final), BG = 1.0
    float4 t0 = *(const float4*)&tm[c0ch];
    out[(c0ch+0)*HW + pixi] = (acc0.x + bgT)*t0.x;
    out[(c0ch+1)*HW + pixi] = (acc0.y + bgT)*t0.y;
    out[(c0ch+2)*HW + pixi] = (acc0.z + bgT)*t0.z;
    out[(c0ch+3)*HW + pixi] = (acc0.w + bgT)*t0.w;
    if (g1ok) {
      const int c1 = c0ch + 16;
      float4 t1 = *(const float4*)&tm[c1];
      out[(c1+0)*HW + pixi] = (acc1.x + bgT)*t1.x;
      out[(c1+1)*HW + pixi] = (acc1.y + bgT)*t1.y;
      out[(c1+2)*HW + pixi] = (acc1.z + bgT)*t1.z;
      out[(c1+3)*HW + pixi] = (acc1.w + bgT)*t1.w;
    }
    if (cq == 2 && w == 0) out[N_C*HW + pixi] = dacc;          // depth
    if (cq == 3 && w == 0) out[N_C*HW + HW + pixi] = 1.0f - T; // A_final
  }
}

extern "C" void kernel_launch(void* const* d_in, const int* in_sizes, int n_in,
                              void* d_out, int out_size, void* d_ws, size_t ws_size,
                              hipStream_t stream) {
  const float* pos    = (const float*)d_in[0];
  // d_in[1] rotations: unused by the reference
  const float* scales = (const float*)d_in[2];
  const float* opac   = (const float*)d_in[3];
  const float* spec   = (const float*)d_in[4];
  const float* tm     = (const float*)d_in[5];
  const float* K      = (const float*)d_in[6];
  const float* E      = (const float*)d_in[7];
  float* out = (float*)d_out;
  (void)d_ws; (void)ws_size;   // no workspace needed

  k_render<<<NBLK, 256, 0, stream>>>(pos, scales, opac, K, E, spec, tm, out);
}